// Round 6
// baseline (241.973 us; speedup 1.0000x reference)
//
#include <hip/hip_runtime.h>
#include <hip/hip_bf16.h>
#include <math.h>

// Problem constants (GraphAttentionReadout)
#define BB 128      // batch
#define NN 2048     // nodes
#define ND 128      // NODE_DIM
#define QD 256      // QUERY_DIM
#define OD 256      // OUT_DIM
#define CHUNKS 16   // N-chunks per batch
#define ROWS_PER_CHUNK (NN / CHUNKS)     // 128 rows per block
#define TILE_ROWS 16                     // rows per LDS tile (8 KB)
#define TILES (ROWS_PER_CHUNK / TILE_ROWS)  // 8
#define PART_STRIDE 260                  // l1,l2,(2 spare), W1[128], W2[128]

// hardware v_exp_f32 computes 2^x directly (~1 ULP)
#define EXP2F(x) __builtin_amdgcn_exp2f(x)

// ---------------------------------------------------------------------------
// Kernel 1: per-batch projections.
//   qk{1,2} = (fp @ Wq{1,2}.T) @ Wk * inv_scale * log2(e)
// ---------------------------------------------------------------------------
__global__ __launch_bounds__(128) void proj_kernel(
    const float* __restrict__ fp_vec, const float* __restrict__ Wq1,
    const float* __restrict__ Wq2, const float* __restrict__ Wk,
    float* __restrict__ qk1g, float* __restrict__ qk2g)
{
  __shared__ __align__(16) float fp_s[QD];
  __shared__ float q1_s[ND];
  __shared__ float q2_s[ND];
  const int b = blockIdx.x, t = threadIdx.x;
  fp_s[t]       = fp_vec[b * QD + t];
  fp_s[t + 128] = fp_vec[b * QD + 128 + t];
  __syncthreads();
  float a1 = 0.f, a2 = 0.f;
  const float4* w1p = (const float4*)(Wq1 + t * QD);
  const float4* w2p = (const float4*)(Wq2 + t * QD);
  #pragma unroll 8
  for (int q = 0; q < QD / 4; ++q) {
    float4 wa = w1p[q], wb = w2p[q];
    float4 f = *(const float4*)&fp_s[q * 4];
    a1 += f.x * wa.x + f.y * wa.y + f.z * wa.z + f.w * wa.w;
    a2 += f.x * wb.x + f.y * wb.y + f.z * wb.z + f.w * wb.w;
  }
  q1_s[t] = a1;
  q2_s[t] = a2;
  __syncthreads();
  float k1 = 0.f, k2 = 0.f;
  #pragma unroll 8
  for (int e = 0; e < ND; ++e) {
    float wv = Wk[e * ND + t];   // coalesced across threads
    k1 += q1_s[e] * wv;
    k2 += q2_s[e] * wv;
  }
  // 1/sqrt(128) * log2(e)
  const float cscale = 0.08838834764831845f * 1.4426950408889634f;
  qk1g[b * ND + t] = k1 * cscale;
  qk2g[b * ND + t] = k2 * cscale;
}

// ---------------------------------------------------------------------------
// Kernel 2: streaming pass over node_mat, dual softmax with FIXED exp2
// reference (shift-invariant; score scale O(1); masked rows -> exact 0).
//
// R6 change: LDS double-buffered staging. R1-R5 all plateaued at attn ~75 us
// (~1.8 TB/s): the compiler sinks register "prefetch" loads back to their
// uses (each load feeds a dependent dot->shuffle->exp chain), leaving ~1
// load in flight per wave. Here tile t+1's global loads feed a ds_write
// that sits BEYOND a barrier, so they must issue before compute(t) and stay
// in flight across it: 8 KB/block outstanding, 7 blocks/CU -> ~56 KB/CU,
// enough to saturate HBM even at several-thousand-cycle loaded latency.
//
// Grid: BB*CHUNKS = 2048 blocks, 256 threads (4 waves). Per tile each wave
// computes 4 rows as 2 half-pair iterations (lanes 0-31 even row, 32-63 odd).
// ---------------------------------------------------------------------------
__global__ __launch_bounds__(256) void attn_kernel(
    const float* __restrict__ node, const int* __restrict__ mask,
    const float* __restrict__ qk1g, const float* __restrict__ qk2g,
    float* __restrict__ part)
{
  const int bid = blockIdx.x;
  const int b = bid >> 4;              // bid / CHUNKS
  const int c = bid & (CHUNKS - 1);
  const int t = threadIdx.x;
  const int wave = t >> 6;
  const int lane = t & 63;
  const int half = lane >> 5;          // 0: even row of pair, 1: odd row
  const int hl = lane & 31;            // owns d = 4*hl .. 4*hl+3

  __shared__ __align__(16) float tile_s[2][TILE_ROWS * ND];  // 2 x 8 KB
  __shared__ float pad_s[ROWS_PER_CHUNK];                    // 512 B
  __shared__ float sl1[4], sl2[4];
  __shared__ __align__(16) float sw1[4][ND], sw2[4][ND];     // 4 KB

  // hoist mask -> additive pad in exp2 domain
  const int chunk_row0 = c * ROWS_PER_CHUNK;
  if (t < ROWS_PER_CHUNK)
    pad_s[t] = mask[b * NN + chunk_row0 + t] ? 0.f : -1e9f;

  const float4 qk1 = *(const float4*)(qk1g + b * ND + hl * 4);
  const float4 qk2 = *(const float4*)(qk2g + b * ND + hl * 4);

  // chunk base as float4; tile tt = float4 indices [tt*512, (tt+1)*512)
  const float4* gc = (const float4*)(node + (size_t)b * NN * ND
                                     + (size_t)chunk_row0 * ND);

  // prologue: stage tile 0 (2 coalesced float4 per thread)
  {
    float4 a0 = gc[t];
    float4 a1 = gc[t + 256];
    float4* d = (float4*)tile_s[0];
    d[t] = a0;
    d[t + 256] = a1;
  }
  __syncthreads();

  float l1 = 0.f, l2 = 0.f;
  float4 w1 = make_float4(0.f, 0.f, 0.f, 0.f);
  float4 w2 = make_float4(0.f, 0.f, 0.f, 0.f);

  #pragma unroll
  for (int tt = 0; tt < TILES; ++tt) {
    // issue next tile's loads; consumer (ds_write) is beyond the barrier,
    // so these stay in flight across the whole compute section
    float4 y0, y1;
    if (tt + 1 < TILES) {
      y0 = gc[(tt + 1) * (TILE_ROWS * ND / 4) + t];
      y1 = gc[(tt + 1) * (TILE_ROWS * ND / 4) + t + 256];
    }
    __builtin_amdgcn_sched_barrier(0);   // pin prefetch above compute

    const float* buf = tile_s[tt & 1];
    #pragma unroll
    for (int i = 0; i < 2; ++i) {
      const int r = 4 * wave + 2 * i + half;          // row within tile
      const float4 x = *(const float4*)&buf[r * ND + hl * 4];
      const float pad = pad_s[tt * TILE_ROWS + r];

      float d1 = x.x * qk1.x + x.y * qk1.y + x.z * qk1.z + x.w * qk1.w;
      float d2 = x.x * qk2.x + x.y * qk2.y + x.z * qk2.z + x.w * qk2.w;
      #pragma unroll
      for (int off = 1; off < 32; off <<= 1) {   // stays within 32-lane half
        d1 += __shfl_xor(d1, off, 64);
        d2 += __shfl_xor(d2, off, 64);
      }
      const float p1 = EXP2F(d1 + pad);
      const float p2 = EXP2F(d2 + pad);
      l1 += p1;
      l2 += p2;
      w1.x += p1 * x.x; w1.y += p1 * x.y; w1.z += p1 * x.z; w1.w += p1 * x.w;
      w2.x += p2 * x.x; w2.y += p2 * x.y; w2.z += p2 * x.z; w2.w += p2 * x.w;
    }
    __syncthreads();                    // all waves done reading other buffer
    if (tt + 1 < TILES) {
      float4* d = (float4*)tile_s[(tt + 1) & 1];
      d[t] = y0;                        // forces vmcnt drain here, not earlier
      d[t + 256] = y1;
    }
    __syncthreads();                    // tile t+1 visible
  }

  // combine: halves within each wave via shfl_xor(32), then 4 waves via LDS
  l1 += __shfl_xor(l1, 32, 64);
  l2 += __shfl_xor(l2, 32, 64);
  w1.x += __shfl_xor(w1.x, 32, 64); w1.y += __shfl_xor(w1.y, 32, 64);
  w1.z += __shfl_xor(w1.z, 32, 64); w1.w += __shfl_xor(w1.w, 32, 64);
  w2.x += __shfl_xor(w2.x, 32, 64); w2.y += __shfl_xor(w2.y, 32, 64);
  w2.z += __shfl_xor(w2.z, 32, 64); w2.w += __shfl_xor(w2.w, 32, 64);
  if (half == 0) {
    *(float4*)&sw1[wave][hl * 4] = w1;
    *(float4*)&sw2[wave][hl * 4] = w2;
    if (hl == 0) { sl1[wave] = l1; sl2[wave] = l2; }
  }
  __syncthreads();

  float* po = part + (size_t)bid * PART_STRIDE;
  if (t == 0) {
    po[0] = sl1[0] + sl1[1] + sl1[2] + sl1[3];
    po[1] = sl2[0] + sl2[1] + sl2[2] + sl2[3];
  }
  if (t < ND) {
    po[4 + t]   = sw1[0][t] + sw1[1][t] + sw1[2][t] + sw1[3][t];
    po[132 + t] = sw2[0][t] + sw2[1][t] + sw2[2][t] + sw2[3][t];
  }
}

// ---------------------------------------------------------------------------
// Kernel 3: sum chunk partials, wd = W1/L1 - lam*W2/L2, z = wd @ Wv.T,
// then LayerNorm over OD=256. Grid: BB blocks, 256 threads.
// ---------------------------------------------------------------------------
__global__ __launch_bounds__(256) void finish_kernel(
    const float* __restrict__ part, const float* __restrict__ Wv,
    const float* __restrict__ lambda_logit, const float* __restrict__ gamma,
    const float* __restrict__ beta, float* __restrict__ out)
{
  const int b = blockIdx.x, t = threadIdx.x;
  __shared__ __align__(16) float wd_s[ND];
  __shared__ float red[8];

  const float lam = 0.8f + 0.2f / (1.f + __expf(-lambda_logit[0]));
  const float* pb = part + (size_t)b * CHUNKS * PART_STRIDE;

  if (t < ND) {
    float L1 = 0.f, L2 = 0.f, W1 = 0.f, W2 = 0.f;
    #pragma unroll
    for (int i = 0; i < CHUNKS; ++i) {
      const float* pc = pb + (size_t)i * PART_STRIDE;
      L1 += pc[0];
      L2 += pc[1];
      W1 += pc[4 + t];
      W2 += pc[132 + t];
    }
    wd_s[t] = W1 / L1 - lam * (W2 / L2);
  }
  __syncthreads();

  // z[o=t] = sum_d wd[d] * Wv[o,d]
  float z = 0.f;
  const float4* wvp = (const float4*)(Wv + t * ND);
  #pragma unroll 8
  for (int d = 0; d < ND / 4; ++d) {
    const float4 w = wvp[d];
    const float4 f = *(const float4*)&wd_s[d * 4];
    z += f.x * w.x + f.y * w.y + f.z * w.z + f.w * w.w;
  }

  // LayerNorm over the 256 outputs of this batch
  const int wave = t >> 6, lane = t & 63;
  float s = z;
  #pragma unroll
  for (int off = 32; off; off >>= 1) s += __shfl_xor(s, off, 64);
  if (lane == 0) red[wave] = s;
  __syncthreads();
  const float mu = (red[0] + red[1] + red[2] + red[3]) * (1.f / OD);
  const float dz = z - mu;
  float vs = dz * dz;
  #pragma unroll
  for (int off = 32; off; off >>= 1) vs += __shfl_xor(vs, off, 64);
  if (lane == 0) red[wave + 4] = vs;   // disjoint slots from red[0..3]
  __syncthreads();
  const float var = (red[4] + red[5] + red[6] + red[7]) * (1.f / OD);
  out[b * OD + t] = dz * rsqrtf(var + 1e-5f) * gamma[t] + beta[t];
}

// ---------------------------------------------------------------------------
extern "C" void kernel_launch(void* const* d_in, const int* in_sizes, int n_in,
                              void* d_out, int out_size, void* d_ws, size_t ws_size,
                              hipStream_t stream) {
  const float* fp_vec = (const float*)d_in[0];
  const float* node   = (const float*)d_in[1];
  const int*   mask   = (const int*)d_in[2];   // bool -> int32 per harness convention
  const float* Wq1    = (const float*)d_in[3];
  const float* Wq2    = (const float*)d_in[4];
  const float* Wk     = (const float*)d_in[5];
  const float* Wv     = (const float*)d_in[6];
  const float* ll     = (const float*)d_in[7];
  const float* gamma  = (const float*)d_in[8];
  const float* beta   = (const float*)d_in[9];
  float* out = (float*)d_out;

  // workspace layout (floats): qk1[B*128] | qk2[B*128] | partials[B*CHUNKS*260]
  float* qk1g = (float*)d_ws;
  float* qk2g = qk1g + BB * ND;
  float* part = qk2g + BB * ND;

  proj_kernel<<<BB, 128, 0, stream>>>(fp_vec, Wq1, Wq2, Wk, qk1g, qk2g);
  attn_kernel<<<BB * CHUNKS, 256, 0, stream>>>(node, mask, qk1g, qk2g, part);
  finish_kernel<<<BB, 256, 0, stream>>>(part, Wv, ll, gamma, beta, out);
}

// Round 7
// 238.358 us; speedup vs baseline: 1.0152x; 1.0152x over previous
//
#include <hip/hip_runtime.h>
#include <hip/hip_bf16.h>
#include <math.h>

// Problem constants (GraphAttentionReadout)
#define BB 128      // batch
#define NN 2048     // nodes
#define ND 128      // NODE_DIM
#define QD 256      // QUERY_DIM
#define OD 256      // OUT_DIM
#define CHUNKS 32   // N-chunks per batch
#define ROWS_PER_CHUNK (NN / CHUNKS)     // 64 rows per block (32 KB)
#define PART_STRIDE 260                  // l1,l2,(2 spare), W1[128], W2[128]

// hardware v_exp_f32 computes 2^x directly (~1 ULP)
#define EXP2F(x) __builtin_amdgcn_exp2f(x)

typedef __attribute__((address_space(1))) const void gvoid_t;
typedef __attribute__((address_space(3))) void lvoid_t;

// ---------------------------------------------------------------------------
// Kernel 1: per-batch projections.
//   qk{1,2} = (fp @ Wq{1,2}.T) @ Wk * inv_scale * log2(e)
// ---------------------------------------------------------------------------
__global__ __launch_bounds__(128) void proj_kernel(
    const float* __restrict__ fp_vec, const float* __restrict__ Wq1,
    const float* __restrict__ Wq2, const float* __restrict__ Wk,
    float* __restrict__ qk1g, float* __restrict__ qk2g)
{
  __shared__ __align__(16) float fp_s[QD];
  __shared__ float q1_s[ND];
  __shared__ float q2_s[ND];
  const int b = blockIdx.x, t = threadIdx.x;
  fp_s[t]       = fp_vec[b * QD + t];
  fp_s[t + 128] = fp_vec[b * QD + 128 + t];
  __syncthreads();
  float a1 = 0.f, a2 = 0.f;
  const float4* w1p = (const float4*)(Wq1 + t * QD);
  const float4* w2p = (const float4*)(Wq2 + t * QD);
  #pragma unroll 8
  for (int q = 0; q < QD / 4; ++q) {
    float4 wa = w1p[q], wb = w2p[q];
    float4 f = *(const float4*)&fp_s[q * 4];
    a1 += f.x * wa.x + f.y * wa.y + f.z * wa.z + f.w * wa.w;
    a2 += f.x * wb.x + f.y * wb.y + f.z * wb.z + f.w * wb.w;
  }
  q1_s[t] = a1;
  q2_s[t] = a2;
  __syncthreads();
  float k1 = 0.f, k2 = 0.f;
  #pragma unroll 8
  for (int e = 0; e < ND; ++e) {
    float wv = Wk[e * ND + t];   // coalesced across threads
    k1 += q1_s[e] * wv;
    k2 += q2_s[e] * wv;
  }
  // 1/sqrt(128) * log2(e)
  const float cscale = 0.08838834764831845f * 1.4426950408889634f;
  qk1g[b * ND + t] = k1 * cscale;
  qk2g[b * ND + t] = k2 * cscale;
}

// ---------------------------------------------------------------------------
// Kernel 2: streaming pass over node_mat, dual softmax with FIXED exp2
// reference (shift-invariant; score scale O(1); masked rows -> exact 0).
//
// R7 change: stage via the ASYNC DMA path (__builtin_amdgcn_global_load_lds,
// width=16). R1-R6 all plateaued at ~75 us (~2.9 B/cyc/CU) across four
// different VGPR-mediated staging structures — the cap is in the per-CU
// memory path, not in software-visible outstanding loads. The DMA path is
// the one empirically proven to break this on gfx950 (m93->m97: 517->874 TF
// from width-16 global_load_lds alone). Each wave DMAs its OWN 8 KB
// (rows 16w..16w+15, contiguous, wave-uniform LDS base + lane*16 — the
// exact layout the instruction requires), one barrier (its implicit
// vmcnt(0) is the DMA completion wait), then computes from LDS.
// Resident blocks (~4/CU, 37 KB LDS) stagger DMA vs compute.
//
// Grid: BB*CHUNKS = 4096 blocks, 256 threads (4 waves). Each wave: 16 rows
// as 8 half-pair iterations (lanes 0-31 even row, 32-63 odd; float4/lane).
// ---------------------------------------------------------------------------
__global__ __launch_bounds__(256) void attn_kernel(
    const float* __restrict__ node, const int* __restrict__ mask,
    const float* __restrict__ qk1g, const float* __restrict__ qk2g,
    float* __restrict__ part)
{
  const int bid = blockIdx.x;
  const int b = bid >> 5;              // bid / CHUNKS
  const int c = bid & (CHUNKS - 1);
  const int t = threadIdx.x;
  const int wave = t >> 6;
  const int lane = t & 63;
  const int half = lane >> 5;          // 0: even row of pair, 1: odd row
  const int hl = lane & 31;            // owns d = 4*hl .. 4*hl+3

  __shared__ __align__(16) float tile_s[ROWS_PER_CHUNK * ND];  // 32 KB
  __shared__ float pad_s[ROWS_PER_CHUNK];                      // 256 B
  __shared__ float sl1[4], sl2[4];
  __shared__ __align__(16) float sw1[4][ND], sw2[4][ND];       // 4 KB

  // hoist mask -> additive pad in exp2 domain
  const int chunk_row0 = c * ROWS_PER_CHUNK;
  if (t < ROWS_PER_CHUNK)
    pad_s[t] = mask[b * NN + chunk_row0 + t] ? 0.f : -1e9f;

  // async DMA: wave w stages its own rows [16w, 16w+16) = 8 KB as 8 x 1 KB.
  // Per-lane global addr = seg + lane*16; LDS dest = wave-uniform seg base
  // (+ lane*16 applied by hardware) -> identity copy into tile_s.
  {
    const char* gb = (const char*)(node + (size_t)b * NN * ND
                                   + (size_t)chunk_row0 * ND);
    const char* gw = gb + wave * 8192 + lane * 16;
    char* lw = ((char*)tile_s) + wave * 8192;
    #pragma unroll
    for (int i = 0; i < 8; ++i) {
      __builtin_amdgcn_global_load_lds(
          (gvoid_t*)(gw + i * 1024),
          (lvoid_t*)(lw + i * 1024),
          16, 0, 0);
    }
  }

  const float4 qk1 = *(const float4*)(qk1g + b * ND + hl * 4);
  const float4 qk2 = *(const float4*)(qk2g + b * ND + hl * 4);

  __syncthreads();   // implicit vmcnt(0): DMA complete; pad_s visible

  float l1 = 0.f, l2 = 0.f;
  float4 w1 = make_float4(0.f, 0.f, 0.f, 0.f);
  float4 w2 = make_float4(0.f, 0.f, 0.f, 0.f);

  #pragma unroll
  for (int j = 0; j < 8; ++j) {
    const int r = 16 * wave + 2 * j + half;          // row within chunk
    const float4 x = *(const float4*)&tile_s[r * ND + hl * 4];
    const float pad = pad_s[r];

    float d1 = x.x * qk1.x + x.y * qk1.y + x.z * qk1.z + x.w * qk1.w;
    float d2 = x.x * qk2.x + x.y * qk2.y + x.z * qk2.z + x.w * qk2.w;
    #pragma unroll
    for (int off = 1; off < 32; off <<= 1) {   // stays within 32-lane half
      d1 += __shfl_xor(d1, off, 64);
      d2 += __shfl_xor(d2, off, 64);
    }
    const float p1 = EXP2F(d1 + pad);
    const float p2 = EXP2F(d2 + pad);
    l1 += p1;
    l2 += p2;
    w1.x += p1 * x.x; w1.y += p1 * x.y; w1.z += p1 * x.z; w1.w += p1 * x.w;
    w2.x += p2 * x.x; w2.y += p2 * x.y; w2.z += p2 * x.z; w2.w += p2 * x.w;
  }

  // combine: halves within each wave via shfl_xor(32), then 4 waves via LDS
  l1 += __shfl_xor(l1, 32, 64);
  l2 += __shfl_xor(l2, 32, 64);
  w1.x += __shfl_xor(w1.x, 32, 64); w1.y += __shfl_xor(w1.y, 32, 64);
  w1.z += __shfl_xor(w1.z, 32, 64); w1.w += __shfl_xor(w1.w, 32, 64);
  w2.x += __shfl_xor(w2.x, 32, 64); w2.y += __shfl_xor(w2.y, 32, 64);
  w2.z += __shfl_xor(w2.z, 32, 64); w2.w += __shfl_xor(w2.w, 32, 64);
  if (half == 0) {
    *(float4*)&sw1[wave][hl * 4] = w1;
    *(float4*)&sw2[wave][hl * 4] = w2;
    if (hl == 0) { sl1[wave] = l1; sl2[wave] = l2; }
  }
  __syncthreads();

  float* po = part + (size_t)bid * PART_STRIDE;
  if (t == 0) {
    po[0] = sl1[0] + sl1[1] + sl1[2] + sl1[3];
    po[1] = sl2[0] + sl2[1] + sl2[2] + sl2[3];
  }
  if (t < ND) {
    po[4 + t]   = sw1[0][t] + sw1[1][t] + sw1[2][t] + sw1[3][t];
    po[132 + t] = sw2[0][t] + sw2[1][t] + sw2[2][t] + sw2[3][t];
  }
}

// ---------------------------------------------------------------------------
// Kernel 3: sum chunk partials, wd = W1/L1 - lam*W2/L2, z = wd @ Wv.T,
// then LayerNorm over OD=256. Grid: BB blocks, 256 threads.
// ---------------------------------------------------------------------------
__global__ __launch_bounds__(256) void finish_kernel(
    const float* __restrict__ part, const float* __restrict__ Wv,
    const float* __restrict__ lambda_logit, const float* __restrict__ gamma,
    const float* __restrict__ beta, float* __restrict__ out)
{
  const int b = blockIdx.x, t = threadIdx.x;
  __shared__ __align__(16) float wd_s[ND];
  __shared__ float red[8];

  const float lam = 0.8f + 0.2f / (1.f + __expf(-lambda_logit[0]));
  const float* pb = part + (size_t)b * CHUNKS * PART_STRIDE;

  if (t < ND) {
    float L1 = 0.f, L2 = 0.f, W1 = 0.f, W2 = 0.f;
    #pragma unroll 8
    for (int i = 0; i < CHUNKS; ++i) {
      const float* pc = pb + (size_t)i * PART_STRIDE;
      L1 += pc[0];
      L2 += pc[1];
      W1 += pc[4 + t];
      W2 += pc[132 + t];
    }
    wd_s[t] = W1 / L1 - lam * (W2 / L2);
  }
  __syncthreads();

  // z[o=t] = sum_d wd[d] * Wv[o,d]
  float z = 0.f;
  const float4* wvp = (const float4*)(Wv + t * ND);
  #pragma unroll 8
  for (int d = 0; d < ND / 4; ++d) {
    const float4 w = wvp[d];
    const float4 f = *(const float4*)&wd_s[d * 4];
    z += f.x * w.x + f.y * w.y + f.z * w.z + f.w * w.w;
  }

  // LayerNorm over the 256 outputs of this batch
  const int wave = t >> 6, lane = t & 63;
  float s = z;
  #pragma unroll
  for (int off = 32; off; off >>= 1) s += __shfl_xor(s, off, 64);
  if (lane == 0) red[wave] = s;
  __syncthreads();
  const float mu = (red[0] + red[1] + red[2] + red[3]) * (1.f / OD);
  const float dz = z - mu;
  float vs = dz * dz;
  #pragma unroll
  for (int off = 32; off; off >>= 1) vs += __shfl_xor(vs, off, 64);
  if (lane == 0) red[wave + 4] = vs;   // disjoint slots from red[0..3]
  __syncthreads();
  const float var = (red[4] + red[5] + red[6] + red[7]) * (1.f / OD);
  out[b * OD + t] = dz * rsqrtf(var + 1e-5f) * gamma[t] + beta[t];
}

// ---------------------------------------------------------------------------
extern "C" void kernel_launch(void* const* d_in, const int* in_sizes, int n_in,
                              void* d_out, int out_size, void* d_ws, size_t ws_size,
                              hipStream_t stream) {
  const float* fp_vec = (const float*)d_in[0];
  const float* node   = (const float*)d_in[1];
  const int*   mask   = (const int*)d_in[2];   // bool -> int32 per harness convention
  const float* Wq1    = (const float*)d_in[3];
  const float* Wq2    = (const float*)d_in[4];
  const float* Wk     = (const float*)d_in[5];
  const float* Wv     = (const float*)d_in[6];
  const float* ll     = (const float*)d_in[7];
  const float* gamma  = (const float*)d_in[8];
  const float* beta   = (const float*)d_in[9];
  float* out = (float*)d_out;

  // workspace layout (floats): qk1[B*128] | qk2[B*128] | partials[B*CHUNKS*260]
  float* qk1g = (float*)d_ws;
  float* qk2g = qk1g + BB * ND;
  float* part = qk2g + BB * ND;

  proj_kernel<<<BB, 128, 0, stream>>>(fp_vec, Wq1, Wq2, Wk, qk1g, qk2g);
  attn_kernel<<<BB * CHUNKS, 256, 0, stream>>>(node, mask, qk1g, qk2g, part);
  finish_kernel<<<BB, 256, 0, stream>>>(part, Wv, ll, gamma, beta, out);
}